// Round 1
// 2093.979 us; speedup vs baseline: 1.3896x; 1.3896x over previous
//
#include <hip/hip_runtime.h>
#include <cfloat>

// N=50000, C=128, H=4, HC=512, E=600000, T=3, Et=200000
// GAT(2x3) -> biLSTM JK -> pool -> MLP. GEMMs in bf16 MFMA (fp32 accum).
// GAT aggregation: dst-bucketed CSR (built once, reused by both layers) +
// fused wave-per-node max/softmax/gather kernel (no atomics on hot path).

typedef __attribute__((ext_vector_type(8))) short short8;
typedef __attribute__((ext_vector_type(4))) float f32x4;

#define DEG_CAP 32   // P(Poisson(4) >= 32) ~ 1e-18; safe for 150k node-type slots

__device__ __forceinline__ float lrelu(float x, float s) { return x > 0.f ? x : s * x; }
__device__ __forceinline__ float sigm(float x) { return 1.f / (1.f + expf(-x)); }

__device__ __forceinline__ unsigned f2bf(float f) {   // RNE f32->bf16 (bits)
    unsigned u = __float_as_uint(f);
    return (u + 0x7FFFu + ((u >> 16) & 1u)) >> 16;
}

// ---------------- bf16 MFMA GEMM: C[M,512] = A[M,128](f32) @ Bt^T + bias (+=C if accum)
// Bt is prepacked bf16 [512][128] (col-major-in-k: Bt[n][k] = B[k][n])
__global__ __launch_bounds__(256) void gemm_mfma(
    const float* __restrict__ A, const ushort* __restrict__ Bt,
    float* __restrict__ C, const float* __restrict__ bias1,
    const float* __restrict__ bias2, int M, int accum)
{
    __shared__ char lds[65536];          // A tile 32KB | B tile 32KB
    char* ldsA = lds;
    char* ldsB = lds + 32768;
    const int tid = threadIdx.x;
    const int row0 = blockIdx.x * 128;
    const int col0 = blockIdx.y * 128;

    // stage A: 128 rows x 128 k, f32->bf16, XOR-swizzled rows
#pragma unroll
    for (int it = 0; it < 8; ++it) {
        int idx = it * 256 + tid;
        int r = idx >> 4, kc = (idx & 15) << 3;
        int row = row0 + r;
        float4 v0 = make_float4(0.f, 0.f, 0.f, 0.f), v1 = v0;
        if (row < M) {
            const float* ap = A + (long)row * 128 + kc;
            v0 = *(const float4*)ap;
            v1 = *(const float4*)(ap + 4);
        }
        uint4 w;
        w.x = f2bf(v0.x) | (f2bf(v0.y) << 16);
        w.y = f2bf(v0.z) | (f2bf(v0.w) << 16);
        w.z = f2bf(v1.x) | (f2bf(v1.y) << 16);
        w.w = f2bf(v1.z) | (f2bf(v1.w) << 16);
        *(uint4*)(ldsA + ((r * 256 + kc * 2) ^ ((r & 7) << 4))) = w;
    }
    // stage B: 128 cols x 128 k bf16 (already [n][k])
#pragma unroll
    for (int it = 0; it < 8; ++it) {
        int idx = it * 256 + tid;
        int cl = idx >> 4, kc = (idx & 15) << 3;
        uint4 w = *(const uint4*)(Bt + (long)(col0 + cl) * 128 + kc);
        *(uint4*)(ldsB + ((cl * 256 + kc * 2) ^ ((cl & 7) << 4))) = w;
    }
    __syncthreads();

    const int wv = tid >> 6, lane = tid & 63;
    const int wr = (wv >> 1) * 64, wc = (wv & 1) * 64;
    const int lr = lane & 15;
    const int lk = (lane >> 4) << 4;     // 16-byte k-offset per 16-lane group
    f32x4 acc[4][4] = {};

#pragma unroll
    for (int ks = 0; ks < 4; ++ks) {
        int kb = ks * 64 + lk;
        short8 af[4], bfr[4];
#pragma unroll
        for (int i = 0; i < 4; ++i) {
            int r = wr + i * 16 + lr;
            af[i] = *(const short8*)(ldsA + ((r * 256 + kb) ^ ((r & 7) << 4)));
            int c = wc + i * 16 + lr;
            bfr[i] = *(const short8*)(ldsB + ((c * 256 + kb) ^ ((c & 7) << 4)));
        }
#pragma unroll
        for (int i = 0; i < 4; ++i)
#pragma unroll
            for (int j = 0; j < 4; ++j)
                acc[i][j] = __builtin_amdgcn_mfma_f32_16x16x32_bf16(af[i], bfr[j], acc[i][j], 0, 0, 0);
    }

    // epilogue: C/D layout col=lane&15, row=(lane>>4)*4+q
#pragma unroll
    for (int j = 0; j < 4; ++j) {
        int col = col0 + wc + j * 16 + lr;
        float bb = 0.f;
        if (bias1) bb += bias1[col];
        if (bias2) bb += bias2[col];
#pragma unroll
        for (int i = 0; i < 4; ++i) {
#pragma unroll
            for (int q = 0; q < 4; ++q) {
                int row = row0 + wr + i * 16 + (lane >> 4) * 4 + q;
                if (row < M) {
                    float* cp = C + (long)row * 512 + col;
                    float v = acc[i][j][q] + bb;
                    if (accum) v += *cp;
                    *cp = v;
                }
            }
        }
    }
}

// ---------------- weight prepack
// gatW [6][128][512] f32 -> out [6][512][128] bf16 (transposed)
__global__ void pack_gatw(const float* __restrict__ gw, ushort* __restrict__ out) {
    int i = blockIdx.x * 256 + threadIdx.x;
    if (i >= 6 * 65536) return;
    int pt = i >> 16, rem = i & 65535, n = rem >> 7, k = rem & 127;
    out[i] = (ushort)f2bf(gw[pt * 65536 + k * 512 + n]);
}
// 4 LSTM weights [512][128] f32 -> bf16 (already [n][k])
__global__ void pack_lstm(const float* __restrict__ a, const float* __restrict__ b,
                          const float* __restrict__ c, const float* __restrict__ d,
                          ushort* __restrict__ out) {
    int i = blockIdx.x * 256 + threadIdx.x;
    if (i >= 4 * 65536) return;
    const float* p = (i < 65536) ? a : (i < 131072) ? b : (i < 196608) ? c : d;
    out[i] = (ushort)f2bf(p[i & 65535]);
}

// ---------------- attention alphas
__global__ __launch_bounds__(128) void att_kernel(
    const float* __restrict__ xp, const float* __restrict__ a_s,
    const float* __restrict__ a_d, float* __restrict__ als,
    float* __restrict__ ald, int N)
{
    int n = blockIdx.x;
    int c = threadIdx.x;
    const float* xr = xp + (long)n * 512;
    float ps[4], pd[4];
#pragma unroll
    for (int h = 0; h < 4; ++h) {
        float v = xr[h * 128 + c];
        ps[h] = v * a_s[h * 128 + c];
        pd[h] = v * a_d[h * 128 + c];
    }
#pragma unroll
    for (int off = 32; off; off >>= 1) {
#pragma unroll
        for (int h = 0; h < 4; ++h) {
            ps[h] += __shfl_down(ps[h], off);
            pd[h] += __shfl_down(pd[h], off);
        }
    }
    __shared__ float sm[2][8];
    int lane = c & 63, w = c >> 6;
    if (lane == 0) {
#pragma unroll
        for (int h = 0; h < 4; ++h) { sm[w][h] = ps[h]; sm[w][4 + h] = pd[h]; }
    }
    __syncthreads();
    if (c < 4) als[(long)n * 4 + c] = sm[0][c] + sm[1][c];
    else if (c < 8) ald[(long)n * 4 + (c - 4)] = sm[0][c] + sm[1][c];
}

// ---------------- CSR build: bucket incoming edges by dst (per edge type)
// bucket[(t*N+d)*DEG_CAP + slot] = src node of that edge
__global__ __launch_bounds__(256) void build_csr(
    const int* __restrict__ srcs, const int* __restrict__ dsts,
    int E, int Et, int N, int* __restrict__ cnt, int* __restrict__ bucket)
{
    int i = blockIdx.x * 256 + threadIdx.x;
    if (i >= E) return;
    int t = i / Et;
    int s = srcs[i];
    int d = dsts[i];
    int slot = atomicAdd(&cnt[t * N + d], 1);
    if (slot < DEG_CAP) bucket[((long)(t * N + d)) * DEG_CAP + slot] = s;
}

// ---------------- fused GAT aggregation: one wave per dst node
// max -> softmax denom (shfl reductions over edge lanes) -> register gather of
// alpha-weighted xp[src] rows -> accb += lrelu(msg + bias, 0.01). No atomics.
__global__ __launch_bounds__(256) void gat_gather(
    const int* __restrict__ cnt, const int* __restrict__ bucket,
    const float* __restrict__ als, const float* __restrict__ ald,
    const float* __restrict__ xp, const float* __restrict__ bias,
    float* __restrict__ accb, int N, int t)
{
    int d = blockIdx.x * 4 + (threadIdx.x >> 6);
    int lane = threadIdx.x & 63;
    if (d >= N) return;
    int deg = min(cnt[t * N + d], DEG_CAP);
    // lane j < deg: edge j; lane == deg: self loop
    int s = d;
    if (lane < deg) s = bucket[((long)(t * N + d)) * DEG_CAP + lane];
    bool act = (lane <= deg);
    float4 ad = *(const float4*)(ald + (long)d * 4);
    float l0 = -FLT_MAX, l1 = -FLT_MAX, l2 = -FLT_MAX, l3 = -FLT_MAX;
    if (act) {
        float4 as = *(const float4*)(als + (long)s * 4);
        l0 = lrelu(as.x + ad.x, 0.2f);
        l1 = lrelu(as.y + ad.y, 0.2f);
        l2 = lrelu(as.z + ad.z, 0.2f);
        l3 = lrelu(as.w + ad.w, 0.2f);
    }
    // wave max
    float m0 = l0, m1 = l1, m2 = l2, m3 = l3;
#pragma unroll
    for (int off = 32; off; off >>= 1) {
        m0 = fmaxf(m0, __shfl_xor(m0, off));
        m1 = fmaxf(m1, __shfl_xor(m1, off));
        m2 = fmaxf(m2, __shfl_xor(m2, off));
        m3 = fmaxf(m3, __shfl_xor(m3, off));
    }
    float e0 = 0.f, e1 = 0.f, e2 = 0.f, e3 = 0.f;
    if (act) {
        e0 = expf(l0 - m0); e1 = expf(l1 - m1);
        e2 = expf(l2 - m2); e3 = expf(l3 - m3);
    }
    // wave denom
    float s0 = e0, s1 = e1, s2 = e2, s3 = e3;
#pragma unroll
    for (int off = 32; off; off >>= 1) {
        s0 += __shfl_xor(s0, off);
        s1 += __shfl_xor(s1, off);
        s2 += __shfl_xor(s2, off);
        s3 += __shfl_xor(s3, off);
    }
    // per-edge alpha (0.25 = mean over heads folded in)
    float a0 = 0.25f * e0 / s0, a1 = 0.25f * e1 / s1;
    float a2 = 0.25f * e2 / s2, a3 = 0.25f * e3 / s3;

    float acc0 = 0.f, acc1 = 0.f;
    for (int j = 0; j <= deg; ++j) {
        int sj = __shfl(s, j);
        float b0 = __shfl(a0, j), b1 = __shfl(a1, j);
        float b2 = __shfl(a2, j), b3 = __shfl(a3, j);
        const float* xs = xp + (long)sj * 512;
        acc0 += b0 * xs[lane]       + b1 * xs[128 + lane]
              + b2 * xs[256 + lane] + b3 * xs[384 + lane];
        acc1 += b0 * xs[64 + lane]  + b1 * xs[192 + lane]
              + b2 * xs[320 + lane] + b3 * xs[448 + lane];
    }
    float* ap = accb + (long)d * 128;
    ap[lane]      += lrelu(acc0 + bias[lane], 0.01f);
    ap[lane + 64] += lrelu(acc1 + bias[lane + 64], 0.01f);
}

__global__ void scale3(float* __restrict__ dst, const float* __restrict__ src, long n) {
    long i = (long)blockIdx.x * 256 + threadIdx.x;
    if (i < n) dst[i] = src[i] * (1.f / 3.f);
}

// LSTM gates + partial JK score
__global__ __launch_bounds__(128) void lstm_gate(
    const float* __restrict__ g, float* __restrict__ h, float* __restrict__ c,
    const float* __restrict__ jkw, float* __restrict__ score, int N)
{
    int n = blockIdx.x, k = threadIdx.x;
    const float* gr = g + (long)n * 512;
    float gi = gr[k], gf = gr[128 + k], gg = gr[256 + k], go = gr[384 + k];
    long off = (long)n * 128 + k;
    float cv = sigm(gf) * c[off] + sigm(gi) * tanhf(gg);
    float hv = sigm(go) * tanhf(cv);
    c[off] = cv;
    h[off] = hv;
    float p = hv * jkw[k];
#pragma unroll
    for (int o = 32; o; o >>= 1) p += __shfl_down(p, o);
    __shared__ float sm[2];
    if ((k & 63) == 0) sm[k >> 6] = p;
    __syncthreads();
    if (k == 0) score[n] += sm[0] + sm[1];
}

__global__ void jk_kernel(const float* __restrict__ score, const float* __restrict__ x0,
                          const float* __restrict__ x1, const float* __restrict__ x2,
                          float* __restrict__ xjk, int N)
{
    long i = (long)blockIdx.x * 256 + threadIdx.x;
    long n = i >> 7;
    if (n >= N) return;
    float s0 = score[n], s1 = score[N + n], s2 = score[2L * N + n];
    float m = fmaxf(s0, fmaxf(s1, s2));
    float e0 = expf(s0 - m), e1 = expf(s1 - m), e2 = expf(s2 - m);
    float inv = 1.f / (e0 + e1 + e2);
    xjk[i] = (e0 * x0[i] + e1 * x1[i] + e2 * x2[i]) * inv;
}

// z0 init: zeros + ptype in col 128
__global__ void init_z0(const float* __restrict__ ptype, float* __restrict__ z0) {
    int i = blockIdx.x * 128 + threadIdx.x;
    if (i < 64 * 129) z0[i] = ((i % 129) == 128) ? ptype[i / 129] : 0.f;
}

// parallel pool: 64-node chunks, flush on graph boundary
__global__ __launch_bounds__(128) void pool2(
    const float* __restrict__ xjk, const int* __restrict__ batch,
    float* __restrict__ z0, int N)
{
    int c = threadIdx.x;
    int n0 = blockIdx.x * 64;
    if (n0 >= N) return;
    int n1 = min(n0 + 64, N);
    float s = 0.f;
    int g = batch[n0];
    for (int n = n0; n < n1; ++n) {
        int b = batch[n];
        if (b != g) { unsafeAtomicAdd(&z0[g * 129 + c], s); s = 0.f; g = b; }
        s += xjk[(long)n * 128 + c];
    }
    unsafeAtomicAdd(&z0[g * 129 + c], s);
}

__global__ __launch_bounds__(128) void mlp_kernel(
    const float* __restrict__ z0, const float* __restrict__ w1, const float* __restrict__ b1,
    const float* __restrict__ w2, const float* __restrict__ b2,
    const float* __restrict__ w3, const float* __restrict__ b3,
    float* __restrict__ out)
{
    int gidx = blockIdx.x, tid = threadIdx.x;
    __shared__ float zin[129], z1[80], z2[80];
    zin[tid] = z0[gidx * 129 + tid];
    if (tid == 0) zin[128] = z0[gidx * 129 + 128];
    __syncthreads();
    if (tid < 80) {
        float s = b1[tid];
        for (int k = 0; k < 129; ++k) s += zin[k] * w1[k * 80 + tid];
        z1[tid] = lrelu(s, 0.01f);
    }
    __syncthreads();
    if (tid < 80) {
        float s = b2[tid];
        for (int k = 0; k < 80; ++k) s += z1[k] * w2[k * 80 + tid];
        z2[tid] = lrelu(s, 0.01f);
    }
    __syncthreads();
    if (tid < 10) {
        float s = b3[tid];
        for (int k = 0; k < 80; ++k) s += z2[k] * w3[k * 10 + tid];
        out[gidx * 10 + tid] = s;
    }
}

extern "C" void kernel_launch(void* const* d_in, const int* in_sizes, int n_in,
                              void* d_out, int out_size, void* d_ws, size_t ws_size,
                              hipStream_t stream)
{
    (void)n_in; (void)out_size; (void)ws_size;
    const float* x      = (const float*)d_in[0];
    const int*   ei     = (const int*)d_in[1];
    const int*   batch  = (const int*)d_in[2];
    const float* ptype  = (const float*)d_in[3];
    const float* gatW   = (const float*)d_in[4];
    const float* gatAs  = (const float*)d_in[5];
    const float* gatAd  = (const float*)d_in[6];
    const float* gatB   = (const float*)d_in[7];
    const float* w_ih_fw = (const float*)d_in[8];
    const float* w_hh_fw = (const float*)d_in[9];
    const float* b_ih_fw = (const float*)d_in[10];
    const float* b_hh_fw = (const float*)d_in[11];
    const float* w_ih_bw = (const float*)d_in[12];
    const float* w_hh_bw = (const float*)d_in[13];
    const float* b_ih_bw = (const float*)d_in[14];
    const float* b_hh_bw = (const float*)d_in[15];
    const float* jkw    = (const float*)d_in[16];
    const float* fc1w   = (const float*)d_in[18];
    const float* fc1b   = (const float*)d_in[19];
    const float* fc2w   = (const float*)d_in[20];
    const float* fc2b   = (const float*)d_in[21];
    const float* fc3w   = (const float*)d_in[22];
    const float* fc3b   = (const float*)d_in[23];

    const int N = in_sizes[0] / 128;
    const int E = in_sizes[1] / 2;
    const int Et = E / 3;
    const long NC = (long)N * 128;

    float* w = (float*)d_ws;
    float* xp   = w; w += (long)N * 512;    // projections / LSTM gates
    float* l1   = w; w += NC;
    float* l2   = w; w += NC;
    float* accb = w; w += NC;               // GAT acc, later xjk
    float* outm = w; w += NC;               // GAT phase: CSR cnt+bucket; later LSTM c
    float* hbuf = w; w += NC;               // LSTM h
    float* als  = w; w += (long)N * 4;
    float* ald  = w; w += (long)N * 4;
    float* score = w; w += 3L * N;
    ushort* gwt = (ushort*)w; w += 6 * 65536 / 2;   // bf16 GAT weights [6][512][128]
    ushort* lwt = (ushort*)w; w += 4 * 65536 / 2;   // bf16 LSTM weights
    float* z0   = w; w += 64 * 129 + 4;

    // CSR aliases the outm region (free until the LSTM phase):
    // cnt: 3*N ints, bucket: 3*N*DEG_CAP ints -> 19.8 MB < 25.6 MB
    int* cnt    = (int*)outm;
    int* bucket = cnt + 3L * N;

    pack_gatw<<<(6 * 65536 + 255) / 256, 256, 0, stream>>>(gatW, gwt);
    pack_lstm<<<(4 * 65536 + 255) / 256, 256, 0, stream>>>(w_ih_fw, w_hh_fw, w_ih_bw, w_hh_bw, lwt);
    hipMemsetAsync(score, 0, sizeof(float) * 3 * N, stream);
    hipMemsetAsync(cnt, 0, sizeof(int) * 3 * N, stream);
    build_csr<<<(E + 255) / 256, 256, 0, stream>>>(ei, ei + E, E, Et, N, cnt, bucket);

    dim3 ggrid((N + 127) / 128, 4);
    const int ncb = (int)((NC + 255) / 256);

    // ---- GAT layers
    const float* cur = x;
    for (int p = 0; p < 2; ++p) {
        hipMemsetAsync(accb, 0, sizeof(float) * NC, stream);
        for (int t = 0; t < 3; ++t) {
            int pt = p * 3 + t;
            gemm_mfma<<<ggrid, 256, 0, stream>>>(cur, gwt + (long)pt * 65536, xp,
                                                 nullptr, nullptr, N, 0);
            att_kernel<<<N, 128, 0, stream>>>(xp, gatAs + pt * 512, gatAd + pt * 512,
                                              als, ald, N);
            gat_gather<<<(N + 3) / 4, 256, 0, stream>>>(cnt, bucket, als, ald, xp,
                                                        gatB + pt * 128, accb, N, t);
        }
        float* dst = (p == 0) ? l1 : l2;
        scale3<<<ncb, 256, 0, stream>>>(dst, accb, NC);
        cur = dst;
    }

    // ---- bi-LSTM over [x, l1, l2] + JK attention scores
    for (int dir = 0; dir < 2; ++dir) {
        const ushort* wih = lwt + (dir ? 2L * 65536 : 0);
        const ushort* whh = lwt + (dir ? 3L * 65536 : 1L * 65536);
        const float* bi = dir ? b_ih_bw : b_ih_fw;
        const float* bh = dir ? b_hh_bw : b_hh_fw;
        hipMemsetAsync(hbuf, 0, sizeof(float) * NC, stream);
        hipMemsetAsync(outm, 0, sizeof(float) * NC, stream);  // c state
        for (int j = 0; j < 3; ++j) {
            int l = dir ? (2 - j) : j;
            const float* s = (l == 0) ? x : (l == 1 ? l1 : l2);
            gemm_mfma<<<ggrid, 256, 0, stream>>>(s, wih, xp, bi, bh, N, 0);
            if (j > 0)
                gemm_mfma<<<ggrid, 256, 0, stream>>>(hbuf, whh, xp, nullptr, nullptr, N, 1);
            lstm_gate<<<N, 128, 0, stream>>>(xp, hbuf, outm, jkw + (dir ? 128 : 0),
                                             score + (long)l * N, N);
        }
    }

    // ---- JK softmax-weighted sum, pool, MLP
    jk_kernel<<<ncb, 256, 0, stream>>>(score, x, l1, l2, accb, N);
    init_z0<<<65, 128, 0, stream>>>(ptype, z0);
    pool2<<<(N + 63) / 64, 128, 0, stream>>>(accb, batch, z0, N);
    mlp_kernel<<<64, 128, 0, stream>>>(z0, fc1w, fc1b, fc2w, fc2b, fc3w, fc3b,
                                       (float*)d_out);
}

// Round 2
// 1220.927 us; speedup vs baseline: 2.3832x; 1.7151x over previous
//
#include <hip/hip_runtime.h>
#include <cfloat>

// N=50000, C=128, H=4, HC=512, E=600000, T=3, Et=200000
// GAT(2x3) -> biLSTM JK -> pool -> MLP. GEMMs in bf16 MFMA (fp32 accum).
// R2: XCD-chunked col-fastest tile swizzle (A panel L2 reuse), 512-thr GEMM
// blocks (2 blk/CU), att fused into GAT GEMM epilogue, dual-K fused LSTM GEMM,
// bias+lrelu+1/3 folded into gat_gather.

typedef __attribute__((ext_vector_type(8))) short short8;
typedef __attribute__((ext_vector_type(4))) float f32x4;

#define DEG_CAP 32   // P(Poisson(4) >= 32) ~ 1e-18

__device__ __forceinline__ float lrelu(float x, float s) { return x > 0.f ? x : s * x; }
__device__ __forceinline__ float sigm(float x) { return 1.f / (1.f + expf(-x)); }

__device__ __forceinline__ unsigned f2bf(float f) {   // RNE f32->bf16 (bits)
    unsigned u = __float_as_uint(f);
    return (u + 0x7FFFu + ((u >> 16) & 1u)) >> 16;
}

// bijective XCD-chunked swizzle (m204): consecutive tiles land on one XCD
__device__ __forceinline__ int xcd_tile(int bid, int nwg) {
    int q = nwg >> 3, r = nwg & 7;
    int xcd = bid & 7, idx = bid >> 3;
    return (xcd < r ? xcd * (q + 1) : r * (q + 1) + (xcd - r) * q) + idx;
}

// stage 128x128 A (f32->bf16, XOR-swizzled) + 128x128 B (bf16) into LDS. 512 thr.
__device__ __forceinline__ void stage_tiles(
    char* ldsA, char* ldsB, const float* __restrict__ A,
    const ushort* __restrict__ Bt, int row0, int col0, int M, int tid)
{
#pragma unroll
    for (int it = 0; it < 4; ++it) {
        int idx = it * 512 + tid;
        int r = idx >> 4, kc = (idx & 15) << 3;
        int row = row0 + r;
        float4 v0 = make_float4(0.f, 0.f, 0.f, 0.f), v1 = v0;
        if (row < M) {
            const float* ap = A + (long)row * 128 + kc;
            v0 = *(const float4*)ap;
            v1 = *(const float4*)(ap + 4);
        }
        uint4 w;
        w.x = f2bf(v0.x) | (f2bf(v0.y) << 16);
        w.y = f2bf(v0.z) | (f2bf(v0.w) << 16);
        w.z = f2bf(v1.x) | (f2bf(v1.y) << 16);
        w.w = f2bf(v1.z) | (f2bf(v1.w) << 16);
        int off = (r * 256 + kc * 2) ^ ((r & 7) << 4);
        *(uint4*)(ldsA + off) = w;
        *(uint4*)(ldsB + off) = *(const uint4*)(Bt + (long)(col0 + r) * 128 + kc);
    }
}

// per-wave 32x64 MFMA tile compute (8 waves cover 128x128)
__device__ __forceinline__ void compute_tile(
    const char* ldsA, const char* ldsB, f32x4 acc[2][4],
    int wr, int wc, int lr, int lk)
{
#pragma unroll
    for (int ks = 0; ks < 4; ++ks) {
        int kb = ks * 64 + lk;
        short8 af[2], bfr[4];
#pragma unroll
        for (int i = 0; i < 2; ++i) {
            int r = wr + i * 16 + lr;
            af[i] = *(const short8*)(ldsA + ((r * 256 + kb) ^ ((r & 7) << 4)));
        }
#pragma unroll
        for (int j = 0; j < 4; ++j) {
            int c = wc + j * 16 + lr;
            bfr[j] = *(const short8*)(ldsB + ((c * 256 + kb) ^ ((c & 7) << 4)));
        }
#pragma unroll
        for (int i = 0; i < 2; ++i)
#pragma unroll
            for (int j = 0; j < 4; ++j)
                acc[i][j] = __builtin_amdgcn_mfma_f32_16x16x32_bf16(af[i], bfr[j], acc[i][j], 0, 0, 0);
    }
}

// ---------------- GAT GEMM: xp[M,512] = A @ Bt^T ; fused als/ald (att dots)
__global__ __launch_bounds__(512, 4) void gemm_att(
    const float* __restrict__ A, const ushort* __restrict__ Bt,
    float* __restrict__ C, const float* __restrict__ a_s,
    const float* __restrict__ a_d, float* __restrict__ als,
    float* __restrict__ ald, int M, int nwg)
{
    __shared__ char lds[65536];
    __shared__ float smS[128], smD[128];
    char* ldsA = lds;
    char* ldsB = lds + 32768;
    const int tid = threadIdx.x;
    int tile = xcd_tile(blockIdx.x, nwg);
    int row0 = (tile >> 2) * 128;
    int h = tile & 3;                 // col tile == head
    int col0 = h * 128;
    if (tid < 128) { smS[tid] = 0.f; smD[tid] = 0.f; }
    stage_tiles(ldsA, ldsB, A, Bt, row0, col0, M, tid);
    __syncthreads();

    const int wv = tid >> 6, lane = tid & 63;
    const int wr = (wv & 3) * 32, wc = (wv >> 2) * 64;
    const int lr = lane & 15;
    const int lk = (lane >> 4) << 4;
    f32x4 acc[2][4] = {};
    compute_tile(ldsA, ldsB, acc, wr, wc, lr, lk);

    const float* asl = a_s + h * 128;
    const float* adl = a_d + h * 128;
    // C write + att partial dots
#pragma unroll
    for (int i = 0; i < 2; ++i) {
#pragma unroll
        for (int q = 0; q < 4; ++q) {
            float ps = 0.f, pd = 0.f;
            int row = row0 + wr + i * 16 + (lane >> 4) * 4 + q;
#pragma unroll
            for (int j = 0; j < 4; ++j) {
                int cc = wc + j * 16 + lr;
                float v = acc[i][j][q];
                ps += v * asl[cc];
                pd += v * adl[cc];
                if (row < M) C[(long)row * 512 + col0 + cc] = v;
            }
#pragma unroll
            for (int off = 8; off; off >>= 1) {
                ps += __shfl_xor(ps, off);
                pd += __shfl_xor(pd, off);
            }
            if (lr == 0) {
                int rl = wr + i * 16 + (lane >> 4) * 4 + q;
                atomicAdd(&smS[rl], ps);
                atomicAdd(&smD[rl], pd);
            }
        }
    }
    __syncthreads();
    if (tid < 128) {
        int row = row0 + tid;
        if (row < M) {
            als[(long)row * 4 + h] = smS[tid];
            ald[(long)row * 4 + h] = smD[tid];
        }
    }
}

// ---------------- LSTM GEMM: C = A1@Bt1^T [+ A2@Bt2^T] + bias1 + bias2
__global__ __launch_bounds__(512, 4) void gemm_lstm(
    const float* __restrict__ A1, const ushort* __restrict__ Bt1,
    const float* __restrict__ A2, const ushort* __restrict__ Bt2,
    const float* __restrict__ bias1, const float* __restrict__ bias2,
    float* __restrict__ C, int M, int nwg)
{
    __shared__ char lds[65536];
    char* ldsA = lds;
    char* ldsB = lds + 32768;
    const int tid = threadIdx.x;
    int tile = xcd_tile(blockIdx.x, nwg);
    int row0 = (tile >> 2) * 128;
    int col0 = (tile & 3) * 128;

    const int wv = tid >> 6, lane = tid & 63;
    const int wr = (wv & 3) * 32, wc = (wv >> 2) * 64;
    const int lr = lane & 15;
    const int lk = (lane >> 4) << 4;
    f32x4 acc[2][4] = {};

    stage_tiles(ldsA, ldsB, A1, Bt1, row0, col0, M, tid);
    __syncthreads();
    compute_tile(ldsA, ldsB, acc, wr, wc, lr, lk);
    if (A2) {
        __syncthreads();
        stage_tiles(ldsA, ldsB, A2, Bt2, row0, col0, M, tid);
        __syncthreads();
        compute_tile(ldsA, ldsB, acc, wr, wc, lr, lk);
    }

#pragma unroll
    for (int j = 0; j < 4; ++j) {
        int cc = wc + j * 16 + lr;
        int col = col0 + cc;
        float bb = 0.f;
        if (bias1) bb += bias1[col];
        if (bias2) bb += bias2[col];
#pragma unroll
        for (int i = 0; i < 2; ++i) {
#pragma unroll
            for (int q = 0; q < 4; ++q) {
                int row = row0 + wr + i * 16 + (lane >> 4) * 4 + q;
                if (row < M) C[(long)row * 512 + col] = acc[i][j][q] + bb;
            }
        }
    }
}

// ---------------- weight prepack
__global__ void pack_gatw(const float* __restrict__ gw, ushort* __restrict__ out) {
    int i = blockIdx.x * 256 + threadIdx.x;
    if (i >= 6 * 65536) return;
    int pt = i >> 16, rem = i & 65535, n = rem >> 7, k = rem & 127;
    out[i] = (ushort)f2bf(gw[pt * 65536 + k * 512 + n]);
}
__global__ void pack_lstm(const float* __restrict__ a, const float* __restrict__ b,
                          const float* __restrict__ c, const float* __restrict__ d,
                          ushort* __restrict__ out) {
    int i = blockIdx.x * 256 + threadIdx.x;
    if (i >= 4 * 65536) return;
    const float* p = (i < 65536) ? a : (i < 131072) ? b : (i < 196608) ? c : d;
    out[i] = (ushort)f2bf(p[i & 65535]);
}

// ---------------- CSR build: bucket incoming edges by dst (per edge type)
__global__ __launch_bounds__(256) void build_csr(
    const int* __restrict__ srcs, const int* __restrict__ dsts,
    int E, int Et, int N, int* __restrict__ cnt, int* __restrict__ bucket)
{
    int i = blockIdx.x * 256 + threadIdx.x;
    if (i >= E) return;
    int t = i / Et;
    int s = srcs[i];
    int d = dsts[i];
    int slot = atomicAdd(&cnt[t * N + d], 1);
    if (slot < DEG_CAP) bucket[((long)(t * N + d)) * DEG_CAP + slot] = s;
}

// ---------------- fused GAT aggregation: one wave per dst node
// writes dst += (or =) lrelu(msg + bias, 0.01) / 3  (no atomics, no scale pass)
__global__ __launch_bounds__(256) void gat_gather(
    const int* __restrict__ cnt, const int* __restrict__ bucket,
    const float* __restrict__ als, const float* __restrict__ ald,
    const float* __restrict__ xp, const float* __restrict__ bias,
    float* __restrict__ dstb, int N, int t, int first)
{
    int d = blockIdx.x * 4 + (threadIdx.x >> 6);
    int lane = threadIdx.x & 63;
    if (d >= N) return;
    int deg = min(cnt[t * N + d], DEG_CAP);
    int s = d;
    if (lane < deg) s = bucket[((long)(t * N + d)) * DEG_CAP + lane];
    bool act = (lane <= deg);
    float4 ad = *(const float4*)(ald + (long)d * 4);
    float l0 = -FLT_MAX, l1 = -FLT_MAX, l2 = -FLT_MAX, l3 = -FLT_MAX;
    if (act) {
        float4 as = *(const float4*)(als + (long)s * 4);
        l0 = lrelu(as.x + ad.x, 0.2f);
        l1 = lrelu(as.y + ad.y, 0.2f);
        l2 = lrelu(as.z + ad.z, 0.2f);
        l3 = lrelu(as.w + ad.w, 0.2f);
    }
    float m0 = l0, m1 = l1, m2 = l2, m3 = l3;
#pragma unroll
    for (int off = 32; off; off >>= 1) {
        m0 = fmaxf(m0, __shfl_xor(m0, off));
        m1 = fmaxf(m1, __shfl_xor(m1, off));
        m2 = fmaxf(m2, __shfl_xor(m2, off));
        m3 = fmaxf(m3, __shfl_xor(m3, off));
    }
    float e0 = 0.f, e1 = 0.f, e2 = 0.f, e3 = 0.f;
    if (act) {
        e0 = expf(l0 - m0); e1 = expf(l1 - m1);
        e2 = expf(l2 - m2); e3 = expf(l3 - m3);
    }
    float s0 = e0, s1 = e1, s2 = e2, s3 = e3;
#pragma unroll
    for (int off = 32; off; off >>= 1) {
        s0 += __shfl_xor(s0, off);
        s1 += __shfl_xor(s1, off);
        s2 += __shfl_xor(s2, off);
        s3 += __shfl_xor(s3, off);
    }
    float a0 = 0.25f * e0 / s0, a1 = 0.25f * e1 / s1;
    float a2 = 0.25f * e2 / s2, a3 = 0.25f * e3 / s3;

    float acc0 = 0.f, acc1 = 0.f;
    for (int j = 0; j <= deg; ++j) {
        int sj = __shfl(s, j);
        float b0 = __shfl(a0, j), b1 = __shfl(a1, j);
        float b2 = __shfl(a2, j), b3 = __shfl(a3, j);
        const float* xs = xp + (long)sj * 512;
        acc0 += b0 * xs[lane]       + b1 * xs[128 + lane]
              + b2 * xs[256 + lane] + b3 * xs[384 + lane];
        acc1 += b0 * xs[64 + lane]  + b1 * xs[192 + lane]
              + b2 * xs[320 + lane] + b3 * xs[448 + lane];
    }
    float r0 = lrelu(acc0 + bias[lane], 0.01f) * (1.f / 3.f);
    float r1 = lrelu(acc1 + bias[lane + 64], 0.01f) * (1.f / 3.f);
    float* ap = dstb + (long)d * 128;
    if (first) { ap[lane] = r0; ap[lane + 64] = r1; }
    else       { ap[lane] += r0; ap[lane + 64] += r1; }
}

// LSTM gates + partial JK score
__global__ __launch_bounds__(128) void lstm_gate(
    const float* __restrict__ g, float* __restrict__ h, float* __restrict__ c,
    const float* __restrict__ jkw, float* __restrict__ score, int N)
{
    int n = blockIdx.x, k = threadIdx.x;
    const float* gr = g + (long)n * 512;
    float gi = gr[k], gf = gr[128 + k], gg = gr[256 + k], go = gr[384 + k];
    long off = (long)n * 128 + k;
    float cv = sigm(gf) * c[off] + sigm(gi) * tanhf(gg);
    float hv = sigm(go) * tanhf(cv);
    c[off] = cv;
    h[off] = hv;
    float p = hv * jkw[k];
#pragma unroll
    for (int o = 32; o; o >>= 1) p += __shfl_down(p, o);
    __shared__ float sm[2];
    if ((k & 63) == 0) sm[k >> 6] = p;
    __syncthreads();
    if (k == 0) score[n] += sm[0] + sm[1];
}

__global__ void jk_kernel(const float* __restrict__ score, const float* __restrict__ x0,
                          const float* __restrict__ x1, const float* __restrict__ x2,
                          float* __restrict__ xjk, int N)
{
    long i = (long)blockIdx.x * 256 + threadIdx.x;
    long n = i >> 7;
    if (n >= N) return;
    float s0 = score[n], s1 = score[N + n], s2 = score[2L * N + n];
    float m = fmaxf(s0, fmaxf(s1, s2));
    float e0 = expf(s0 - m), e1 = expf(s1 - m), e2 = expf(s2 - m);
    float inv = 1.f / (e0 + e1 + e2);
    xjk[i] = (e0 * x0[i] + e1 * x1[i] + e2 * x2[i]) * inv;
}

// z0 init: zeros + ptype in col 128
__global__ void init_z0(const float* __restrict__ ptype, float* __restrict__ z0) {
    int i = blockIdx.x * 128 + threadIdx.x;
    if (i < 64 * 129) z0[i] = ((i % 129) == 128) ? ptype[i / 129] : 0.f;
}

// parallel pool: 64-node chunks, flush on graph boundary
__global__ __launch_bounds__(128) void pool2(
    const float* __restrict__ xjk, const int* __restrict__ batch,
    float* __restrict__ z0, int N)
{
    int c = threadIdx.x;
    int n0 = blockIdx.x * 64;
    if (n0 >= N) return;
    int n1 = min(n0 + 64, N);
    float s = 0.f;
    int g = batch[n0];
    for (int n = n0; n < n1; ++n) {
        int b = batch[n];
        if (b != g) { unsafeAtomicAdd(&z0[g * 129 + c], s); s = 0.f; g = b; }
        s += xjk[(long)n * 128 + c];
    }
    unsafeAtomicAdd(&z0[g * 129 + c], s);
}

__global__ __launch_bounds__(128) void mlp_kernel(
    const float* __restrict__ z0, const float* __restrict__ w1, const float* __restrict__ b1,
    const float* __restrict__ w2, const float* __restrict__ b2,
    const float* __restrict__ w3, const float* __restrict__ b3,
    float* __restrict__ out)
{
    int gidx = blockIdx.x, tid = threadIdx.x;
    __shared__ float zin[129], z1[80], z2[80];
    zin[tid] = z0[gidx * 129 + tid];
    if (tid == 0) zin[128] = z0[gidx * 129 + 128];
    __syncthreads();
    if (tid < 80) {
        float s = b1[tid];
        for (int k = 0; k < 129; ++k) s += zin[k] * w1[k * 80 + tid];
        z1[tid] = lrelu(s, 0.01f);
    }
    __syncthreads();
    if (tid < 80) {
        float s = b2[tid];
        for (int k = 0; k < 80; ++k) s += z1[k] * w2[k * 80 + tid];
        z2[tid] = lrelu(s, 0.01f);
    }
    __syncthreads();
    if (tid < 10) {
        float s = b3[tid];
        for (int k = 0; k < 80; ++k) s += z2[k] * w3[k * 10 + tid];
        out[gidx * 10 + tid] = s;
    }
}

extern "C" void kernel_launch(void* const* d_in, const int* in_sizes, int n_in,
                              void* d_out, int out_size, void* d_ws, size_t ws_size,
                              hipStream_t stream)
{
    (void)n_in; (void)out_size; (void)ws_size;
    const float* x      = (const float*)d_in[0];
    const int*   ei     = (const int*)d_in[1];
    const int*   batch  = (const int*)d_in[2];
    const float* ptype  = (const float*)d_in[3];
    const float* gatW   = (const float*)d_in[4];
    const float* gatAs  = (const float*)d_in[5];
    const float* gatAd  = (const float*)d_in[6];
    const float* gatB   = (const float*)d_in[7];
    const float* w_ih_fw = (const float*)d_in[8];
    const float* w_hh_fw = (const float*)d_in[9];
    const float* b_ih_fw = (const float*)d_in[10];
    const float* b_hh_fw = (const float*)d_in[11];
    const float* w_ih_bw = (const float*)d_in[12];
    const float* w_hh_bw = (const float*)d_in[13];
    const float* b_ih_bw = (const float*)d_in[14];
    const float* b_hh_bw = (const float*)d_in[15];
    const float* jkw    = (const float*)d_in[16];
    const float* fc1w   = (const float*)d_in[18];
    const float* fc1b   = (const float*)d_in[19];
    const float* fc2w   = (const float*)d_in[20];
    const float* fc2b   = (const float*)d_in[21];
    const float* fc3w   = (const float*)d_in[22];
    const float* fc3b   = (const float*)d_in[23];

    const int N = in_sizes[0] / 128;
    const int E = in_sizes[1] / 2;
    const int Et = E / 3;
    const long NC = (long)N * 128;

    float* w = (float*)d_ws;
    float* xp   = w; w += (long)N * 512;    // projections / LSTM gates
    float* l1   = w; w += NC;
    float* l2   = w; w += NC;
    float* accb = w; w += NC;               // xjk
    float* outm = w; w += NC;               // GAT phase: CSR cnt+bucket; later LSTM c
    float* hbuf = w; w += NC;               // LSTM h
    float* als  = w; w += (long)N * 4;
    float* ald  = w; w += (long)N * 4;
    float* score = w; w += 3L * N;
    ushort* gwt = (ushort*)w; w += 6 * 65536 / 2;   // bf16 GAT weights [6][512][128]
    ushort* lwt = (ushort*)w; w += 4 * 65536 / 2;   // bf16 LSTM weights
    float* z0   = w; w += 64 * 129 + 4;

    // CSR aliases the outm region (free until the LSTM phase)
    int* cnt    = (int*)outm;
    int* bucket = cnt + 3L * N;

    pack_gatw<<<(6 * 65536 + 255) / 256, 256, 0, stream>>>(gatW, gwt);
    pack_lstm<<<(4 * 65536 + 255) / 256, 256, 0, stream>>>(w_ih_fw, w_hh_fw, w_ih_bw, w_hh_bw, lwt);
    hipMemsetAsync(score, 0, sizeof(float) * 3 * N, stream);
    hipMemsetAsync(cnt, 0, sizeof(int) * 3 * N, stream);
    build_csr<<<(E + 255) / 256, 256, 0, stream>>>(ei, ei + E, E, Et, N, cnt, bucket);

    const int RB = (N + 127) / 128;
    const int nwg = RB * 4;
    const int ncb = (int)((NC + 255) / 256);

    // ---- GAT layers
    const float* cur = x;
    for (int p = 0; p < 2; ++p) {
        float* dstb = (p == 0) ? l1 : l2;
        for (int t = 0; t < 3; ++t) {
            int pt = p * 3 + t;
            gemm_att<<<nwg, 512, 0, stream>>>(cur, gwt + (long)pt * 65536, xp,
                                              gatAs + pt * 512, gatAd + pt * 512,
                                              als, ald, N, nwg);
            gat_gather<<<(N + 3) / 4, 256, 0, stream>>>(cnt, bucket, als, ald, xp,
                                                        gatB + pt * 128, dstb, N, t,
                                                        t == 0);
        }
        cur = dstb;
    }

    // ---- bi-LSTM over [x, l1, l2] + JK attention scores
    for (int dir = 0; dir < 2; ++dir) {
        const ushort* wih = lwt + (dir ? 2L * 65536 : 0);
        const ushort* whh = lwt + (dir ? 3L * 65536 : 1L * 65536);
        const float* bi = dir ? b_ih_bw : b_ih_fw;
        const float* bh = dir ? b_hh_bw : b_hh_fw;
        hipMemsetAsync(hbuf, 0, sizeof(float) * NC, stream);
        hipMemsetAsync(outm, 0, sizeof(float) * NC, stream);  // c state
        for (int j = 0; j < 3; ++j) {
            int l = dir ? (2 - j) : j;
            const float* s = (l == 0) ? x : (l == 1 ? l1 : l2);
            if (j == 0)
                gemm_lstm<<<nwg, 512, 0, stream>>>(s, wih, nullptr, nullptr,
                                                   bi, bh, xp, N, nwg);
            else
                gemm_lstm<<<nwg, 512, 0, stream>>>(s, wih, hbuf, whh,
                                                   bi, bh, xp, N, nwg);
            lstm_gate<<<N, 128, 0, stream>>>(xp, hbuf, outm, jkw + (dir ? 128 : 0),
                                             score + (long)l * N, N);
        }
    }

    // ---- JK softmax-weighted sum, pool, MLP
    jk_kernel<<<ncb, 256, 0, stream>>>(score, x, l1, l2, accb, N);
    init_z0<<<65, 128, 0, stream>>>(ptype, z0);
    pool2<<<(N + 63) / 64, 128, 0, stream>>>(accb, batch, z0, N);
    mlp_kernel<<<64, 128, 0, stream>>>(z0, fc1w, fc1b, fc2w, fc2b, fc3w, fc3b,
                                       (float*)d_out);
}

// Round 3
// 1210.934 us; speedup vs baseline: 2.4029x; 1.0083x over previous
//
#include <hip/hip_runtime.h>
#include <cfloat>

// N=50000, C=128, H=4, HC=512, E=600000, T=3, Et=200000
// GAT(2x3) -> biLSTM JK -> pool -> MLP. GEMMs in bf16 MFMA (fp32 accum).
// R3: depth-2 software-pipelined gat_gather (rotation registers);
// fully-fused LSTM step (GEMM ih+hh + cell pointwise + bf16 h + JK score
// in one kernel, 64-row panels, 96KB LDS) -- no gate matrix materialized.

typedef __attribute__((ext_vector_type(8))) short short8;
typedef __attribute__((ext_vector_type(4))) float f32x4;

#define DEG_CAP 32   // P(Poisson(4) >= 32) ~ 1e-18

__device__ __forceinline__ float lrelu(float x, float s) { return x > 0.f ? x : s * x; }
__device__ __forceinline__ float sigm(float x) { return 1.f / (1.f + expf(-x)); }

__device__ __forceinline__ unsigned f2bf(float f) {   // RNE f32->bf16 (bits)
    unsigned u = __float_as_uint(f);
    return (u + 0x7FFFu + ((u >> 16) & 1u)) >> 16;
}

// bijective XCD-chunked swizzle (m204): consecutive tiles land on one XCD
__device__ __forceinline__ int xcd_tile(int bid, int nwg) {
    int q = nwg >> 3, r = nwg & 7;
    int xcd = bid & 7, idx = bid >> 3;
    return (xcd < r ? xcd * (q + 1) : r * (q + 1) + (xcd - r) * q) + idx;
}

// stage 128x128 A (f32->bf16, XOR-swizzled) + 128x128 B (bf16) into LDS. 512 thr.
__device__ __forceinline__ void stage_tiles(
    char* ldsA, char* ldsB, const float* __restrict__ A,
    const ushort* __restrict__ Bt, int row0, int col0, int M, int tid)
{
#pragma unroll
    for (int it = 0; it < 4; ++it) {
        int idx = it * 512 + tid;
        int r = idx >> 4, kc = (idx & 15) << 3;
        int row = row0 + r;
        float4 v0 = make_float4(0.f, 0.f, 0.f, 0.f), v1 = v0;
        if (row < M) {
            const float* ap = A + (long)row * 128 + kc;
            v0 = *(const float4*)ap;
            v1 = *(const float4*)(ap + 4);
        }
        uint4 w;
        w.x = f2bf(v0.x) | (f2bf(v0.y) << 16);
        w.y = f2bf(v0.z) | (f2bf(v0.w) << 16);
        w.z = f2bf(v1.x) | (f2bf(v1.y) << 16);
        w.w = f2bf(v1.z) | (f2bf(v1.w) << 16);
        int off = (r * 256 + kc * 2) ^ ((r & 7) << 4);
        *(uint4*)(ldsA + off) = w;
        *(uint4*)(ldsB + off) = *(const uint4*)(Bt + (long)(col0 + r) * 128 + kc);
    }
}

// per-wave 32x64 MFMA tile compute (8 waves cover 128x128)
__device__ __forceinline__ void compute_tile(
    const char* ldsA, const char* ldsB, f32x4 acc[2][4],
    int wr, int wc, int lr, int lk)
{
#pragma unroll
    for (int ks = 0; ks < 4; ++ks) {
        int kb = ks * 64 + lk;
        short8 af[2], bfr[4];
#pragma unroll
        for (int i = 0; i < 2; ++i) {
            int r = wr + i * 16 + lr;
            af[i] = *(const short8*)(ldsA + ((r * 256 + kb) ^ ((r & 7) << 4)));
        }
#pragma unroll
        for (int j = 0; j < 4; ++j) {
            int c = wc + j * 16 + lr;
            bfr[j] = *(const short8*)(ldsB + ((c * 256 + kb) ^ ((c & 7) << 4)));
        }
#pragma unroll
        for (int i = 0; i < 2; ++i)
#pragma unroll
            for (int j = 0; j < 4; ++j)
                acc[i][j] = __builtin_amdgcn_mfma_f32_16x16x32_bf16(af[i], bfr[j], acc[i][j], 0, 0, 0);
    }
}

// ---------------- GAT GEMM: xp[M,512] = A @ Bt^T ; fused als/ald (att dots)
__global__ __launch_bounds__(512, 4) void gemm_att(
    const float* __restrict__ A, const ushort* __restrict__ Bt,
    float* __restrict__ C, const float* __restrict__ a_s,
    const float* __restrict__ a_d, float* __restrict__ als,
    float* __restrict__ ald, int M, int nwg)
{
    __shared__ char lds[65536];
    __shared__ float smS[128], smD[128];
    char* ldsA = lds;
    char* ldsB = lds + 32768;
    const int tid = threadIdx.x;
    int tile = xcd_tile(blockIdx.x, nwg);
    int row0 = (tile >> 2) * 128;
    int h = tile & 3;                 // col tile == head
    int col0 = h * 128;
    if (tid < 128) { smS[tid] = 0.f; smD[tid] = 0.f; }
    stage_tiles(ldsA, ldsB, A, Bt, row0, col0, M, tid);
    __syncthreads();

    const int wv = tid >> 6, lane = tid & 63;
    const int wr = (wv & 3) * 32, wc = (wv >> 2) * 64;
    const int lr = lane & 15;
    const int lk = (lane >> 4) << 4;
    f32x4 acc[2][4] = {};
    compute_tile(ldsA, ldsB, acc, wr, wc, lr, lk);

    const float* asl = a_s + h * 128;
    const float* adl = a_d + h * 128;
#pragma unroll
    for (int i = 0; i < 2; ++i) {
#pragma unroll
        for (int q = 0; q < 4; ++q) {
            float ps = 0.f, pd = 0.f;
            int row = row0 + wr + i * 16 + (lane >> 4) * 4 + q;
#pragma unroll
            for (int j = 0; j < 4; ++j) {
                int cc = wc + j * 16 + lr;
                float v = acc[i][j][q];
                ps += v * asl[cc];
                pd += v * adl[cc];
                if (row < M) C[(long)row * 512 + col0 + cc] = v;
            }
#pragma unroll
            for (int off = 8; off; off >>= 1) {
                ps += __shfl_xor(ps, off);
                pd += __shfl_xor(pd, off);
            }
            if (lr == 0) {
                int rl = wr + i * 16 + (lane >> 4) * 4 + q;
                atomicAdd(&smS[rl], ps);
                atomicAdd(&smD[rl], pd);
            }
        }
    }
    __syncthreads();
    if (tid < 128) {
        int row = row0 + tid;
        if (row < M) {
            als[(long)row * 4 + h] = smS[tid];
            ald[(long)row * 4 + h] = smD[tid];
        }
    }
}

// ---------------- fused LSTM step: gates GEMM (ih + hh) + cell + JK score
// 64-row panel x all 512 gate cols per block; h written as bf16 (next A2).
__global__ __launch_bounds__(512) void lstm_fused(
    const float* __restrict__ A1, const ushort* __restrict__ Bih,
    const ushort* __restrict__ Bhh, ushort* __restrict__ hbuf,
    float* __restrict__ cbuf, const float* __restrict__ bi,
    const float* __restrict__ bh, const float* __restrict__ jkw,
    float* __restrict__ score, int M, int first)
{
    __shared__ char lds[98304];        // A1 16K | A2 16K | B1 32K | B2 32K
    __shared__ float ssc[64];
    char* ldsA1 = lds;
    char* ldsA2 = lds + 16384;
    char* ldsB1 = lds + 32768;
    char* ldsB2 = lds + 65536;
    const int tid = threadIdx.x;
    const int row0 = blockIdx.x * 64;
    if (tid < 64) ssc[tid] = 0.f;

    // stage A1: 64 rows x 128 k, f32->bf16
#pragma unroll
    for (int it = 0; it < 2; ++it) {
        int g = it * 512 + tid;
        int r = g >> 4, kc = (g & 15) << 3;
        int row = row0 + r;
        float4 v0 = make_float4(0.f, 0.f, 0.f, 0.f), v1 = v0;
        if (row < M) {
            const float* ap = A1 + (long)row * 128 + kc;
            v0 = *(const float4*)ap;
            v1 = *(const float4*)(ap + 4);
        }
        uint4 w;
        w.x = f2bf(v0.x) | (f2bf(v0.y) << 16);
        w.y = f2bf(v0.z) | (f2bf(v0.w) << 16);
        w.z = f2bf(v1.x) | (f2bf(v1.y) << 16);
        w.w = f2bf(v1.z) | (f2bf(v1.w) << 16);
        *(uint4*)(ldsA1 + ((r * 256 + kc * 2) ^ ((r & 7) << 4))) = w;
    }
    // stage A2: prev h (bf16) unless first step
    if (!first) {
#pragma unroll
        for (int it = 0; it < 2; ++it) {
            int g = it * 512 + tid;
            int r = g >> 4, kc = (g & 15) << 3;
            int row = row0 + r;
            uint4 w = make_uint4(0, 0, 0, 0);
            if (row < M) w = *(const uint4*)(hbuf + (long)row * 128 + kc);
            *(uint4*)(ldsA2 + ((r * 256 + kc * 2) ^ ((r & 7) << 4))) = w;
        }
    }

    const int wv = tid >> 6, lane = tid & 63;
    const int ws = wv >> 1;            // row strip (16 rows)
    const int wcol = (wv & 1) * 64;    // col half within each 128-chunk
    const int lr = lane & 15;
    const int lk = (lane >> 4) << 4;
    f32x4 acc[4][4] = {};              // [gate chunk][j]

#pragma unroll
    for (int cc = 0; cc < 4; ++cc) {
        __syncthreads();
        // stage B chunk cc for both weight matrices (gate cc rows)
#pragma unroll
        for (int it = 0; it < 4; ++it) {
            int g = it * 512 + tid;
            int r = g >> 4, kc = (g & 15) << 3;
            int off = (r * 256 + kc * 2) ^ ((r & 7) << 4);
            long brow = (long)(cc * 128 + r) * 128 + kc;
            *(uint4*)(ldsB1 + off) = *(const uint4*)(Bih + brow);
            *(uint4*)(ldsB2 + off) = *(const uint4*)(Bhh + brow);
        }
        __syncthreads();
#pragma unroll
        for (int ks = 0; ks < 4; ++ks) {
            int kb = ks * 64 + lk;
            int r = ws * 16 + lr;
            short8 af = *(const short8*)(ldsA1 + ((r * 256 + kb) ^ ((r & 7) << 4)));
#pragma unroll
            for (int j = 0; j < 4; ++j) {
                int c = wcol + j * 16 + lr;
                short8 bfr = *(const short8*)(ldsB1 + ((c * 256 + kb) ^ ((c & 7) << 4)));
                acc[cc][j] = __builtin_amdgcn_mfma_f32_16x16x32_bf16(af, bfr, acc[cc][j], 0, 0, 0);
            }
        }
        if (!first) {
#pragma unroll
            for (int ks = 0; ks < 4; ++ks) {
                int kb = ks * 64 + lk;
                int r = ws * 16 + lr;
                short8 af = *(const short8*)(ldsA2 + ((r * 256 + kb) ^ ((r & 7) << 4)));
#pragma unroll
                for (int j = 0; j < 4; ++j) {
                    int c = wcol + j * 16 + lr;
                    short8 bfr = *(const short8*)(ldsB2 + ((c * 256 + kb) ^ ((c & 7) << 4)));
                    acc[cc][j] = __builtin_amdgcn_mfma_f32_16x16x32_bf16(af, bfr, acc[cc][j], 0, 0, 0);
                }
            }
        }
    }

    // cell pointwise in registers: gi=acc[0], gf=acc[1], gg=acc[2], go=acc[3]
    float psum[4] = {0.f, 0.f, 0.f, 0.f};
#pragma unroll
    for (int j = 0; j < 4; ++j) {
        int k = wcol + j * 16 + lr;
        float bi0 = bi[k] + bh[k];
        float bf0 = bi[128 + k] + bh[128 + k];
        float bg0 = bi[256 + k] + bh[256 + k];
        float bo0 = bi[384 + k] + bh[384 + k];
        float jw = jkw[k];
#pragma unroll
        for (int q = 0; q < 4; ++q) {
            int row = row0 + ws * 16 + (lane >> 4) * 4 + q;
            long off = (long)row * 128 + k;
            float cprev = (!first && row < M) ? cbuf[off] : 0.f;
            float cv = sigm(acc[1][j][q] + bf0) * cprev
                     + sigm(acc[0][j][q] + bi0) * tanhf(acc[2][j][q] + bg0);
            float hv = sigm(acc[3][j][q] + bo0) * tanhf(cv);
            if (row < M) {
                cbuf[off] = cv;
                hbuf[off] = (ushort)f2bf(hv);
            }
            psum[q] += hv * jw;
        }
    }
#pragma unroll
    for (int q = 0; q < 4; ++q) {
        float p = psum[q];
#pragma unroll
        for (int off = 8; off; off >>= 1) p += __shfl_xor(p, off);   // width-16
        if (lr == 0) atomicAdd(&ssc[ws * 16 + (lane >> 4) * 4 + q], p);
    }
    __syncthreads();
    if (tid < 64) {
        int row = row0 + tid;
        if (row < M) score[row] += ssc[tid];
    }
}

// ---------------- weight prepack
__global__ void pack_gatw(const float* __restrict__ gw, ushort* __restrict__ out) {
    int i = blockIdx.x * 256 + threadIdx.x;
    if (i >= 6 * 65536) return;
    int pt = i >> 16, rem = i & 65535, n = rem >> 7, k = rem & 127;
    out[i] = (ushort)f2bf(gw[pt * 65536 + k * 512 + n]);
}
__global__ void pack_lstm(const float* __restrict__ a, const float* __restrict__ b,
                          const float* __restrict__ c, const float* __restrict__ d,
                          ushort* __restrict__ out) {
    int i = blockIdx.x * 256 + threadIdx.x;
    if (i >= 4 * 65536) return;
    const float* p = (i < 65536) ? a : (i < 131072) ? b : (i < 196608) ? c : d;
    out[i] = (ushort)f2bf(p[i & 65535]);
}

// ---------------- CSR build: bucket incoming edges by dst (per edge type)
__global__ __launch_bounds__(256) void build_csr(
    const int* __restrict__ srcs, const int* __restrict__ dsts,
    int E, int Et, int N, int* __restrict__ cnt, int* __restrict__ bucket)
{
    int i = blockIdx.x * 256 + threadIdx.x;
    if (i >= E) return;
    int t = i / Et;
    int s = srcs[i];
    int d = dsts[i];
    int slot = atomicAdd(&cnt[t * N + d], 1);
    if (slot < DEG_CAP) bucket[((long)(t * N + d)) * DEG_CAP + slot] = s;
}

// ---------------- fused GAT aggregation: one wave per dst node, depth-2 SW pipe
__global__ __launch_bounds__(256) void gat_gather(
    const int* __restrict__ cnt, const int* __restrict__ bucket,
    const float* __restrict__ als, const float* __restrict__ ald,
    const float* __restrict__ xp, const float* __restrict__ bias,
    float* __restrict__ dstb, int N, int t, int first)
{
    int d = blockIdx.x * 4 + (threadIdx.x >> 6);
    int lane = threadIdx.x & 63;
    if (d >= N) return;
    int deg = min(cnt[t * N + d], DEG_CAP);
    int s = d;
    if (lane < deg) s = bucket[((long)(t * N + d)) * DEG_CAP + lane];
    bool act = (lane <= deg);
    float4 ad = *(const float4*)(ald + (long)d * 4);
    float l0 = -FLT_MAX, l1 = -FLT_MAX, l2 = -FLT_MAX, l3 = -FLT_MAX;
    if (act) {
        float4 as = *(const float4*)(als + (long)s * 4);
        l0 = lrelu(as.x + ad.x, 0.2f);
        l1 = lrelu(as.y + ad.y, 0.2f);
        l2 = lrelu(as.z + ad.z, 0.2f);
        l3 = lrelu(as.w + ad.w, 0.2f);
    }
    float m0 = l0, m1 = l1, m2 = l2, m3 = l3;
#pragma unroll
    for (int off = 32; off; off >>= 1) {
        m0 = fmaxf(m0, __shfl_xor(m0, off));
        m1 = fmaxf(m1, __shfl_xor(m1, off));
        m2 = fmaxf(m2, __shfl_xor(m2, off));
        m3 = fmaxf(m3, __shfl_xor(m3, off));
    }
    float e0 = 0.f, e1 = 0.f, e2 = 0.f, e3 = 0.f;
    if (act) {
        e0 = expf(l0 - m0); e1 = expf(l1 - m1);
        e2 = expf(l2 - m2); e3 = expf(l3 - m3);
    }
    float s0 = e0, s1 = e1, s2 = e2, s3 = e3;
#pragma unroll
    for (int off = 32; off; off >>= 1) {
        s0 += __shfl_xor(s0, off);
        s1 += __shfl_xor(s1, off);
        s2 += __shfl_xor(s2, off);
        s3 += __shfl_xor(s3, off);
    }
    float a0 = 0.25f * e0 / s0, a1 = 0.25f * e1 / s1;
    float a2 = 0.25f * e2 / s2, a3 = 0.25f * e3 / s3;

    // depth-2 software pipeline over incoming edges (+self)
    float acc0 = 0.f, acc1 = 0.f;
    int sj = __shfl(s, 0);
    const float* xs = xp + (long)sj * 512;
    float c0 = xs[lane],       c1 = xs[64 + lane];
    float c2 = xs[128 + lane], c3 = xs[192 + lane];
    float c4 = xs[256 + lane], c5 = xs[320 + lane];
    float c6 = xs[384 + lane], c7 = xs[448 + lane];
    for (int j = 0; j < deg; ++j) {
        int sn = __shfl(s, j + 1);
        const float* xn = xp + (long)sn * 512;
        float n0 = xn[lane],       n1 = xn[64 + lane];
        float n2 = xn[128 + lane], n3 = xn[192 + lane];
        float n4 = xn[256 + lane], n5 = xn[320 + lane];
        float n6 = xn[384 + lane], n7 = xn[448 + lane];
        float w0 = __shfl(a0, j), w1 = __shfl(a1, j);
        float w2 = __shfl(a2, j), w3 = __shfl(a3, j);
        acc0 += w0 * c0 + w1 * c2 + w2 * c4 + w3 * c6;
        acc1 += w0 * c1 + w1 * c3 + w2 * c5 + w3 * c7;
        c0 = n0; c1 = n1; c2 = n2; c3 = n3;
        c4 = n4; c5 = n5; c6 = n6; c7 = n7;
    }
    float w0 = __shfl(a0, deg), w1 = __shfl(a1, deg);
    float w2 = __shfl(a2, deg), w3 = __shfl(a3, deg);
    acc0 += w0 * c0 + w1 * c2 + w2 * c4 + w3 * c6;
    acc1 += w0 * c1 + w1 * c3 + w2 * c5 + w3 * c7;

    float r0 = lrelu(acc0 + bias[lane], 0.01f) * (1.f / 3.f);
    float r1 = lrelu(acc1 + bias[lane + 64], 0.01f) * (1.f / 3.f);
    float* ap = dstb + (long)d * 128;
    if (first) { ap[lane] = r0; ap[lane + 64] = r1; }
    else       { ap[lane] += r0; ap[lane + 64] += r1; }
}

__global__ void jk_kernel(const float* __restrict__ score, const float* __restrict__ x0,
                          const float* __restrict__ x1, const float* __restrict__ x2,
                          float* __restrict__ xjk, int N)
{
    long i = (long)blockIdx.x * 256 + threadIdx.x;
    long n = i >> 7;
    if (n >= N) return;
    float s0 = score[n], s1 = score[N + n], s2 = score[2L * N + n];
    float m = fmaxf(s0, fmaxf(s1, s2));
    float e0 = expf(s0 - m), e1 = expf(s1 - m), e2 = expf(s2 - m);
    float inv = 1.f / (e0 + e1 + e2);
    xjk[i] = (e0 * x0[i] + e1 * x1[i] + e2 * x2[i]) * inv;
}

// z0 init: zeros + ptype in col 128
__global__ void init_z0(const float* __restrict__ ptype, float* __restrict__ z0) {
    int i = blockIdx.x * 128 + threadIdx.x;
    if (i < 64 * 129) z0[i] = ((i % 129) == 128) ? ptype[i / 129] : 0.f;
}

// parallel pool: 64-node chunks, flush on graph boundary
__global__ __launch_bounds__(128) void pool2(
    const float* __restrict__ xjk, const int* __restrict__ batch,
    float* __restrict__ z0, int N)
{
    int c = threadIdx.x;
    int n0 = blockIdx.x * 64;
    if (n0 >= N) return;
    int n1 = min(n0 + 64, N);
    float s = 0.f;
    int g = batch[n0];
    for (int n = n0; n < n1; ++n) {
        int b = batch[n];
        if (b != g) { unsafeAtomicAdd(&z0[g * 129 + c], s); s = 0.f; g = b; }
        s += xjk[(long)n * 128 + c];
    }
    unsafeAtomicAdd(&z0[g * 129 + c], s);
}

__global__ __launch_bounds__(128) void mlp_kernel(
    const float* __restrict__ z0, const float* __restrict__ w1, const float* __restrict__ b1,
    const float* __restrict__ w2, const float* __restrict__ b2,
    const float* __restrict__ w3, const float* __restrict__ b3,
    float* __restrict__ out)
{
    int gidx = blockIdx.x, tid = threadIdx.x;
    __shared__ float zin[129], z1[80], z2[80];
    zin[tid] = z0[gidx * 129 + tid];
    if (tid == 0) zin[128] = z0[gidx * 129 + 128];
    __syncthreads();
    if (tid < 80) {
        float s = b1[tid];
        for (int k = 0; k < 129; ++k) s += zin[k] * w1[k * 80 + tid];
        z1[tid] = lrelu(s, 0.01f);
    }
    __syncthreads();
    if (tid < 80) {
        float s = b2[tid];
        for (int k = 0; k < 80; ++k) s += z1[k] * w2[k * 80 + tid];
        z2[tid] = lrelu(s, 0.01f);
    }
    __syncthreads();
    if (tid < 10) {
        float s = b3[tid];
        for (int k = 0; k < 80; ++k) s += z2[k] * w3[k * 10 + tid];
        out[gidx * 10 + tid] = s;
    }
}

extern "C" void kernel_launch(void* const* d_in, const int* in_sizes, int n_in,
                              void* d_out, int out_size, void* d_ws, size_t ws_size,
                              hipStream_t stream)
{
    (void)n_in; (void)out_size; (void)ws_size;
    const float* x      = (const float*)d_in[0];
    const int*   ei     = (const int*)d_in[1];
    const int*   batch  = (const int*)d_in[2];
    const float* ptype  = (const float*)d_in[3];
    const float* gatW   = (const float*)d_in[4];
    const float* gatAs  = (const float*)d_in[5];
    const float* gatAd  = (const float*)d_in[6];
    const float* gatB   = (const float*)d_in[7];
    const float* w_ih_fw = (const float*)d_in[8];
    const float* w_hh_fw = (const float*)d_in[9];
    const float* b_ih_fw = (const float*)d_in[10];
    const float* b_hh_fw = (const float*)d_in[11];
    const float* w_ih_bw = (const float*)d_in[12];
    const float* w_hh_bw = (const float*)d_in[13];
    const float* b_ih_bw = (const float*)d_in[14];
    const float* b_hh_bw = (const float*)d_in[15];
    const float* jkw    = (const float*)d_in[16];
    const float* fc1w   = (const float*)d_in[18];
    const float* fc1b   = (const float*)d_in[19];
    const float* fc2w   = (const float*)d_in[20];
    const float* fc2b   = (const float*)d_in[21];
    const float* fc3w   = (const float*)d_in[22];
    const float* fc3b   = (const float*)d_in[23];

    const int N = in_sizes[0] / 128;
    const int E = in_sizes[1] / 2;
    const int Et = E / 3;
    const long NC = (long)N * 128;

    float* w = (float*)d_ws;
    float* xp   = w; w += (long)N * 512;    // GAT projections
    float* l1   = w; w += NC;
    float* l2   = w; w += NC;
    float* accb = w; w += NC;               // xjk
    float* outm = w; w += NC;               // GAT: CSR cnt+bucket; LSTM: c state
    float* hbuf = w; w += NC;               // LSTM h (bf16, half used)
    float* als  = w; w += (long)N * 4;
    float* ald  = w; w += (long)N * 4;
    float* score = w; w += 3L * N;
    ushort* gwt = (ushort*)w; w += 6 * 65536 / 2;   // bf16 GAT weights [6][512][128]
    ushort* lwt = (ushort*)w; w += 4 * 65536 / 2;   // bf16 LSTM weights
    float* z0   = w; w += 64 * 129 + 4;

    // CSR aliases the outm region (free until the LSTM phase)
    int* cnt    = (int*)outm;
    int* bucket = cnt + 3L * N;

    pack_gatw<<<(6 * 65536 + 255) / 256, 256, 0, stream>>>(gatW, gwt);
    pack_lstm<<<(4 * 65536 + 255) / 256, 256, 0, stream>>>(w_ih_fw, w_hh_fw, w_ih_bw, w_hh_bw, lwt);
    hipMemsetAsync(score, 0, sizeof(float) * 3 * N, stream);
    hipMemsetAsync(cnt, 0, sizeof(int) * 3 * N, stream);
    build_csr<<<(E + 255) / 256, 256, 0, stream>>>(ei, ei + E, E, Et, N, cnt, bucket);

    const int RB = (N + 127) / 128;
    const int nwg = RB * 4;
    const int ncb = (int)((NC + 255) / 256);

    // ---- GAT layers
    const float* cur = x;
    for (int p = 0; p < 2; ++p) {
        float* dstb = (p == 0) ? l1 : l2;
        for (int t = 0; t < 3; ++t) {
            int pt = p * 3 + t;
            gemm_att<<<nwg, 512, 0, stream>>>(cur, gwt + (long)pt * 65536, xp,
                                              gatAs + pt * 512, gatAd + pt * 512,
                                              als, ald, N, nwg);
            gat_gather<<<(N + 3) / 4, 256, 0, stream>>>(cnt, bucket, als, ald, xp,
                                                        gatB + pt * 128, dstb, N, t,
                                                        t == 0);
        }
        cur = dstb;
    }

    // ---- fused bi-LSTM over [x, l1, l2] + JK attention scores
    ushort* hb16 = (ushort*)hbuf;
    float* cbuf = outm;                    // CSR dead now
    const int lnb = (N + 63) / 64;
    for (int dir = 0; dir < 2; ++dir) {
        const ushort* wih = lwt + (dir ? 2L * 65536 : 0);
        const ushort* whh = lwt + (dir ? 3L * 65536 : 1L * 65536);
        const float* bi = dir ? b_ih_bw : b_ih_fw;
        const float* bh = dir ? b_hh_bw : b_hh_fw;
        for (int j = 0; j < 3; ++j) {
            int l = dir ? (2 - j) : j;
            const float* s = (l == 0) ? x : (l == 1 ? l1 : l2);
            lstm_fused<<<lnb, 512, 0, stream>>>(s, wih, whh, hb16, cbuf, bi, bh,
                                                jkw + (dir ? 128 : 0),
                                                score + (long)l * N, N, j == 0);
        }
    }

    // ---- JK softmax-weighted sum, pool, MLP
    jk_kernel<<<ncb, 256, 0, stream>>>(score, x, l1, l2, accb, N);
    init_z0<<<65, 128, 0, stream>>>(ptype, z0);
    pool2<<<(N + 63) / 64, 128, 0, stream>>>(accb, batch, z0, N);
    mlp_kernel<<<64, 128, 0, stream>>>(z0, fc1w, fc1b, fc2w, fc2b, fc3w, fc3b,
                                       (float*)d_out);
}